// Round 1
// baseline (351.967 us; speedup 1.0000x reference)
//
#include <hip/hip_runtime.h>
#include <math.h>

#define N_ATOMS   20000
#define N_NBR     32
#define NBR_TOTAL (N_ATOMS * N_NBR)   // 640000 = 2500 * 256
#define N_ELEM    83
#define NUM_EMB   64
#define NUM_RAD   8

// One thread = one neighbor for compute; LDS-staged transpose for coalesced writes.
// LDS: F table (83x8) + per-neighbor scalars (256 x 33: 16 sh, 8 g=t*rbf, 8 t, 1 pad)
__global__ __launch_bounds__(256) void sarb_kernel(
    const float* __restrict__ disp,   // (N, K, 3)
    const int*   __restrict__ Zj,     // (N, K)
    const float* __restrict__ embed,  // (83, 64)
    const float* __restrict__ dw,     // (64, 8)
    const float* __restrict__ db,     // (8,)
    const float* __restrict__ tw,     // (4, 8)
    float* __restrict__ out)          // (N, K, 1, 16, 8) fp32
{
    __shared__ float Fl[N_ELEM * NUM_RAD];   // 664 floats
    __shared__ float lds[256 * 33];          // 33792 B

    const int tid = threadIdx.x;

    // ---- stage 0: fold embed_table @ dense_w + b into F[83][8] (per block) ----
    for (int i = tid; i < N_ELEM * NUM_RAD; i += 256) {
        int z = i >> 3, f = i & 7;
        float acc = db[f];
        const float* er = embed + z * NUM_EMB;
        for (int e = 0; e < NUM_EMB; ++e)
            acc = fmaf(er[e], dw[e * 8 + f], acc);
        Fl[i] = acc;
    }
    __syncthreads();

    // ---- stage 1: per-neighbor scalars -> LDS ----
    const int n = blockIdx.x * 256 + tid;    // grid sized exactly: no guard
    const float dx = disp[n * 3 + 0];
    const float dy = disp[n * 3 + 1];
    const float dz = disp[n * 3 + 2];
    const int   z  = Zj[n];

    const float r2  = dx * dx + dy * dy + dz * dz;
    const float nrm = sqrtf(r2);
    const float inv = 1.0f / nrm;            // nrm > 0 a.s. for gaussian inputs
    const float x = dx * inv, y = dy * inv, zu = dz * inv;

    // spherical harmonics, Racah norm, l<=3, m=-l..l
    const float s3 = 1.7320508075688772f, s6 = 2.449489742783178f;
    const float s10 = 3.1622776601683795f, s15 = 3.872983346207417f;
    const float x2 = x * x, y2 = y * y, z2 = zu * zu;
    const float xy = x * y, yz = y * zu, xz = x * zu;

    const int base = tid * 33;
    lds[base + 0]  = 1.0f;
    lds[base + 1]  = y;
    lds[base + 2]  = zu;
    lds[base + 3]  = x;
    lds[base + 4]  = s3 * xy;
    lds[base + 5]  = s3 * yz;
    lds[base + 6]  = 0.5f * (3.0f * z2 - 1.0f);
    lds[base + 7]  = s3 * xz;
    lds[base + 8]  = 0.5f * s3 * (x2 - y2);
    lds[base + 9]  = 0.25f * s10 * y * (3.0f * x2 - y2);
    lds[base + 10] = s15 * xy * zu;
    lds[base + 11] = 0.25f * s6 * y * (5.0f * z2 - 1.0f);
    lds[base + 12] = 0.5f * zu * (5.0f * z2 - 3.0f);
    lds[base + 13] = 0.25f * s6 * x * (5.0f * z2 - 1.0f);
    lds[base + 14] = 0.5f * s15 * zu * (x2 - y2);
    lds[base + 15] = 0.25f * s10 * x * (x2 - 3.0f * y2);

    // radial: sinc(k*a)/(k*a) for k=1..9 via Chebyshev recurrence, a = pi*r/5
    const float a = 0.6283185307179586f * nrm;
    float sv[9];
    {
        const float s1  = sinf(a);
        const float c2  = 2.0f * cosf(a);
        const float inva = 1.0f / a;
        const float invk[9] = {1.0f, 0.5f, 0.33333333f, 0.25f, 0.2f,
                               0.16666667f, 0.14285714f, 0.125f, 0.11111111f};
        float sprev = 0.0f, scur = s1;
        #pragma unroll
        for (int k = 0; k < 9; ++k) {
            sv[k] = scur * inva * invk[k];
            float snext = c2 * scur - sprev;
            sprev = scur; scur = snext;
        }
        if (a < 1e-12f) {
            #pragma unroll
            for (int k = 0; k < 9; ++k) sv[k] = 1.0f;
        }
    }
    // jinc coefficients: factor1 * (-1)^i (i+1)(i+2)/hypot(i+1,i+2), constant-folded
    #pragma unroll
    for (int i = 0; i < 8; ++i) {
        const float ip1 = (float)(i + 1), ip2 = (float)(i + 2);
        float f2 = ip1 * ip2 / sqrtf(ip1 * ip1 + ip2 * ip2);
        if (i & 1) f2 = -f2;
        const float rbf = 0.3973835397f * f2 * (sv[i] + sv[i + 1]);
        const float tf  = Fl[z * 8 + i];
        lds[base + 16 + i] = tf * rbf;   // g
        lds[base + 24 + i] = tf;         // t (for l=0 residual)
    }
    __syncthreads();

    // ---- stage 2: coalesced float4 writes; chunk = tid&31 is loop-invariant ----
    const int chunk = tid & 31;          // float4 index within a neighbor's 128 floats
    const int lm = chunk >> 1;
    const int fh = (chunk & 1) * 4;
    const int l  = (lm > 0) + (lm > 3) + (lm > 8);
    const float4 wv = *reinterpret_cast<const float4*>(tw + l * 8 + fh);

    float4* outv = reinterpret_cast<float4*>(out) + (size_t)blockIdx.x * 8192;
    const int nb0 = tid >> 5;
    #pragma unroll
    for (int k = 0; k < 32; ++k) {
        const int nb = k * 8 + nb0;
        const int b  = nb * 33;
        const float s = lds[b + lm];
        const float g0 = lds[b + 16 + fh + 0];
        const float g1 = lds[b + 16 + fh + 1];
        const float g2 = lds[b + 16 + fh + 2];
        const float g3 = lds[b + 16 + fh + 3];
        float4 r;
        r.x = wv.x * s * g0;
        r.y = wv.y * s * g1;
        r.z = wv.z * s * g2;
        r.w = wv.w * s * g3;
        if (lm == 0) {
            r.x += lds[b + 24 + fh + 0];
            r.y += lds[b + 24 + fh + 1];
            r.z += lds[b + 24 + fh + 2];
            r.w += lds[b + 24 + fh + 3];
        }
        outv[k * 256 + tid] = r;
    }
}

extern "C" void kernel_launch(void* const* d_in, const int* in_sizes, int n_in,
                              void* d_out, int out_size, void* d_ws, size_t ws_size,
                              hipStream_t stream) {
    const float* disp  = (const float*)d_in[0];
    const int*   Zj    = (const int*)  d_in[1];
    const float* embed = (const float*)d_in[2];
    const float* dw    = (const float*)d_in[3];
    const float* db    = (const float*)d_in[4];
    const float* tw    = (const float*)d_in[5];
    float* out = (float*)d_out;

    sarb_kernel<<<dim3(NBR_TOTAL / 256), dim3(256), 0, stream>>>(
        disp, Zj, embed, dw, db, tw, out);
}

// Round 5
// 344.760 us; speedup vs baseline: 1.0209x; 1.0209x over previous
//
#include <hip/hip_runtime.h>
#include <math.h>

#define N_ATOMS   20000
#define N_NBR     32
#define NBR_TOTAL (N_ATOMS * N_NBR)   // 640000 = 2500 * 256
#define N_ELEM    83
#define NUM_EMB   64
#define ROWW      34                   // 16 sh + 8 g + 8 h + 2 pad (even: float2-aligned)

typedef float f32x4 __attribute__((ext_vector_type(4)));

// ---- tiny pre-kernel: F[z][f] = embed[z]@dense_w[:,f] + db[f], once per launch ----
__global__ __launch_bounds__(256) void f_table_kernel(
    const float* __restrict__ embed, const float* __restrict__ dw,
    const float* __restrict__ db, float* __restrict__ F)
{
    const int i = blockIdx.x * 256 + threadIdx.x;
    if (i < N_ELEM * 8) {
        const int z = i >> 3, f = i & 7;
        float acc = db[f];
        const float* er = embed + z * NUM_EMB;
        #pragma unroll 8
        for (int e = 0; e < NUM_EMB; ++e)
            acc = fmaf(er[e], dw[e * 8 + f], acc);
        F[i] = acc;
    }
}

// One thread = one neighbor for compute; LDS-staged transpose for coalesced writes.
__global__ __launch_bounds__(256) void sarb_kernel(
    const float* __restrict__ disp,   // (N, K, 3)
    const int*   __restrict__ Zj,     // (N, K)
    const float* __restrict__ tw,     // (4, 8)
    const float* __restrict__ Fg,     // (83, 8) precomputed
    float* __restrict__ out)          // (N, K, 1, 16, 8) fp32
{
    __shared__ float Fl[N_ELEM * 9 + 1];          // padded stride 9: gcd(9,32)=1
    __shared__ __align__(16) float lds[256 * ROWW];

    const int tid = threadIdx.x;

    // stage 0: F table global -> LDS (padded)
    for (int i = tid; i < N_ELEM * 8; i += 256)
        Fl[(i >> 3) * 9 + (i & 7)] = Fg[i];
    __syncthreads();

    // ---- stage 1: per-neighbor scalars -> LDS row ----
    const int n = blockIdx.x * 256 + tid;    // grid sized exactly: no guard
    const float dx = disp[3 * n + 0];
    const float dy = disp[3 * n + 1];
    const float dz = disp[3 * n + 2];
    const int   z  = Zj[n];

    const float r2  = dx * dx + dy * dy + dz * dz;
    const float nrm = sqrtf(r2);
    const float inv = 1.0f / nrm;            // nrm > 0 a.s. for gaussian inputs
    const float x = dx * inv, y = dy * inv, zu = dz * inv;

    const float s3 = 1.7320508075688772f, s6 = 2.449489742783178f;
    const float s10 = 3.1622776601683795f, s15 = 3.872983346207417f;
    const float x2 = x * x, y2 = y * y, z2 = zu * zu;
    const float xy = x * y, yz = y * zu, xz = x * zu;

    float* row = lds + tid * ROWW;
    row[0]  = 1.0f;
    row[1]  = y;
    row[2]  = zu;
    row[3]  = x;
    row[4]  = s3 * xy;
    row[5]  = s3 * yz;
    row[6]  = 0.5f * (3.0f * z2 - 1.0f);
    row[7]  = s3 * xz;
    row[8]  = 0.5f * s3 * (x2 - y2);
    row[9]  = 0.25f * s10 * y * (3.0f * x2 - y2);
    row[10] = s15 * xy * zu;
    row[11] = 0.25f * s6 * y * (5.0f * z2 - 1.0f);
    row[12] = 0.5f * zu * (5.0f * z2 - 3.0f);
    row[13] = 0.25f * s6 * x * (5.0f * z2 - 1.0f);
    row[14] = 0.5f * s15 * zu * (x2 - y2);
    row[15] = 0.25f * s10 * x * (x2 - 3.0f * y2);

    // radial: sinc(k*a)/(k*a), k=1..9, Chebyshev recurrence; a = pi*r/5
    const float a = 0.6283185307179586f * nrm;
    float sv[9];
    {
        float s1, c1;
        __sincosf(a, &s1, &c1);
        const float c2   = 2.0f * c1;
        const float inva = 1.0f / a;
        const float invk[9] = {1.0f, 0.5f, 0.33333334f, 0.25f, 0.2f,
                               0.16666667f, 0.14285715f, 0.125f, 0.11111111f};
        float sprev = 0.0f, scur = s1;
        #pragma unroll
        for (int k = 0; k < 9; ++k) {
            sv[k] = scur * inva * invk[k];
            const float snext = c2 * scur - sprev;
            sprev = scur; scur = snext;
        }
        if (a < 1e-12f) {
            #pragma unroll
            for (int k = 0; k < 9; ++k) sv[k] = 1.0f;
        }
    }
    // g = t*rbf; h = t*(tw0*rbf + 1) == full l=0 output incl. residual
    #pragma unroll
    for (int i = 0; i < 8; ++i) {
        const float ip1 = (float)(i + 1), ip2 = (float)(i + 2);
        float f2 = ip1 * ip2 / sqrtf(ip1 * ip1 + ip2 * ip2);
        if (i & 1) f2 = -f2;
        const float rbf = 0.3973835397f * f2 * (sv[i] + sv[i + 1]);
        const float tf  = Fl[z * 9 + i];
        row[16 + i] = tf * rbf;
        row[24 + i] = fmaf(tw[i] * rbf, tf, tf);
    }
    __syncthreads();

    // ---- stage 2: branchless, coalesced nt float4 writes ----
    const int chunk = tid & 31;          // float4 index within a neighbor's 128 floats
    const int lm  = chunk >> 1;
    const int fh4 = chunk & 1;
    const int l   = (lm > 0) + (lm > 3) + (lm > 8);
    f32x4 wv;
    if (lm == 0) { wv = (f32x4){1.0f, 1.0f, 1.0f, 1.0f}; }
    else         { wv = *reinterpret_cast<const f32x4*>(tw + l * 8 + fh4 * 4); }
    const int goff = (lm ? 16 : 24) + fh4 * 4;   // lm==0 lanes read h; s=row[0]=1

    f32x4* __restrict__ outv =
        reinterpret_cast<f32x4*>(out) + (size_t)blockIdx.x * 8192;
    const int nb0 = tid >> 5;
    #pragma unroll
    for (int k = 0; k < 32; ++k) {
        const int rb = (k * 8 + nb0) * ROWW;
        const float  s  = lds[rb + lm];
        const float2 ga = *reinterpret_cast<const float2*>(lds + rb + goff);
        const float2 gb = *reinterpret_cast<const float2*>(lds + rb + goff + 2);
        f32x4 r;
        r.x = wv.x * s * ga.x;
        r.y = wv.y * s * ga.y;
        r.z = wv.z * s * gb.x;
        r.w = wv.w * s * gb.y;
        __builtin_nontemporal_store(r, outv + k * 256 + tid);
    }
}

extern "C" void kernel_launch(void* const* d_in, const int* in_sizes, int n_in,
                              void* d_out, int out_size, void* d_ws, size_t ws_size,
                              hipStream_t stream) {
    const float* disp  = (const float*)d_in[0];
    const int*   Zj    = (const int*)  d_in[1];
    const float* embed = (const float*)d_in[2];
    const float* dw    = (const float*)d_in[3];
    const float* db    = (const float*)d_in[4];
    const float* tw    = (const float*)d_in[5];
    float* out = (float*)d_out;
    float* F   = (float*)d_ws;   // 664 floats of scratch

    f_table_kernel<<<dim3(3), dim3(256), 0, stream>>>(embed, dw, db, F);
    sarb_kernel<<<dim3(NBR_TOTAL / 256), dim3(256), 0, stream>>>(disp, Zj, tw, F, out);
}